// Round 2
// baseline (1062.539 us; speedup 1.0000x reference)
//
#include <hip/hip_runtime.h>

typedef unsigned short u16;
typedef __bf16 bf16x8 __attribute__((ext_vector_type(8)));
typedef float f32x4 __attribute__((ext_vector_type(4)));

#define T_TOKENS 8192
#define DM 1024
#define DH 4096
#define DO 1024
#define NE 8

// workspace layout (bytes)
#define XB_OFF   0ull
#define W1B_OFF  16777216ull
#define W2B_OFF  16777216ull      /* aliases w1b region; cast after gemm1 */
#define H_OFF    83886080ull      /* 16384 x 4096 bf16 = 128 MB */
#define PT_OFF   218103808ull     /* pair_token [16384] int */
#define PG_OFF   218169344ull     /* pair_gate  [16384] float */
#define TI_OFF   218234880ull     /* topk_idx [8192][2] int */
#define TG_OFF   218300416ull     /* topk_gate [8192][2] float */
#define ST_OFF   218365952ull     /* counts[8], cursor[8], offs[8], psum[8] */

#define LSTR 64                   /* unpadded: required by global_load_lds layout */

typedef __attribute__((address_space(3))) void lds_void;
typedef __attribute__((address_space(1))) const void gbl_void;

__device__ __forceinline__ void gload_lds16(const void* g, void* l) {
  __builtin_amdgcn_global_load_lds((gbl_void*)g, (lds_void*)l, 16, 0, 0);
}

__device__ __forceinline__ u16 f2bf(float f) {
  union { float f; unsigned u; } a; a.f = f;
  unsigned u = a.u;
  return (u16)((u + 0x7FFFu + ((u >> 16) & 1u)) >> 16);  // RNE
}

__global__ __launch_bounds__(256) void cast_f32_bf16(const float* __restrict__ src,
                                                     u16* __restrict__ dst, int n4) {
  int i = blockIdx.x * 256 + threadIdx.x;
  if (i >= n4) return;
  float4 v = ((const float4*)src)[i];
  ushort4 o;
  o.x = f2bf(v.x); o.y = f2bf(v.y); o.z = f2bf(v.z); o.w = f2bf(v.w);
  ((ushort4*)dst)[i] = o;
}

__global__ __launch_bounds__(256) void router_kernel(
    const float* __restrict__ x, const float* __restrict__ rw,
    const float* __restrict__ rb,
    int* __restrict__ tidx, float* __restrict__ tgate,
    int* __restrict__ counts, float* __restrict__ psum)
{
  __shared__ float srw[NE * DM];
  __shared__ float s_psum[NE];
  __shared__ int s_cnt[NE];

  for (int i = threadIdx.x; i < NE * DM; i += 256) srw[i] = rw[i];
  if (threadIdx.x < NE) { s_psum[threadIdx.x] = 0.f; s_cnt[threadIdx.x] = 0; }
  __syncthreads();

  const int wave = threadIdx.x >> 6;
  const int lane = threadIdx.x & 63;
  const int t = blockIdx.x * 4 + wave;

  float xv[16];
#pragma unroll
  for (int i = 0; i < 16; i++) xv[i] = x[(size_t)t * DM + i * 64 + lane];

  float logits[8];
#pragma unroll
  for (int e = 0; e < 8; e++) {
    float p = 0.f;
#pragma unroll
    for (int i = 0; i < 16; i++) p += xv[i] * srw[e * DM + i * 64 + lane];
#pragma unroll
    for (int o = 32; o > 0; o >>= 1) p += __shfl_xor(p, o, 64);
    logits[e] = p;
  }

  if (lane == 0) {
    float pe[8];
    float mx = -1e30f;
    for (int e = 0; e < 8; e++) { logits[e] += rb[e]; mx = fmaxf(mx, logits[e]); }
    float s = 0.f;
    for (int e = 0; e < 8; e++) { pe[e] = expf(logits[e] - mx); s += pe[e]; }
    float inv = 1.f / s;
    for (int e = 0; e < 8; e++) { pe[e] *= inv; atomicAdd(&s_psum[e], pe[e]); }
    int i0 = 0;
    for (int e = 1; e < 8; e++) if (pe[e] > pe[i0]) i0 = e;        // ties -> lowest idx
    int i1 = (i0 == 0) ? 1 : 0;
    for (int e = 0; e < 8; e++) if (e != i0 && pe[e] > pe[i1]) i1 = e;
    float g = pe[i0] + pe[i1];
    tidx[t * 2] = i0; tidx[t * 2 + 1] = i1;
    tgate[t * 2] = pe[i0] / g; tgate[t * 2 + 1] = pe[i1] / g;
    atomicAdd(&s_cnt[i0], 1); atomicAdd(&s_cnt[i1], 1);
  }
  __syncthreads();
  if (threadIdx.x < NE) {
    atomicAdd(&counts[threadIdx.x], s_cnt[threadIdx.x]);
    atomicAdd(&psum[threadIdx.x], s_psum[threadIdx.x]);
  }
}

__global__ void offsets_kernel(const int* __restrict__ counts, int* __restrict__ offs) {
  if (threadIdx.x == 0) {
    int a = 0;
    for (int e = 0; e < NE; e++) { offs[e] = a; a += counts[e]; }
  }
}

__global__ __launch_bounds__(256) void scatter_kernel(
    const int* __restrict__ tidx, const float* __restrict__ tgate,
    const int* __restrict__ offs, int* __restrict__ cursor,
    int* __restrict__ ptok, float* __restrict__ pgate)
{
  int t = blockIdx.x * 256 + threadIdx.x;
#pragma unroll
  for (int k = 0; k < 2; k++) {
    int e = tidx[t * 2 + k];
    int pos = offs[e] + atomicAdd(&cursor[e], 1);
    ptok[pos] = t;
    pgate[pos] = tgate[t * 2 + k];
  }
}

// GEMM1: h[p, j] = relu( sum_k xb[tok(p), k] * w1b[e, j, k] + b1[e, j] )
__global__ __launch_bounds__(256) void gemm1_kernel(
    const u16* __restrict__ xb, const u16* __restrict__ w1b,
    const float* __restrict__ b1, const int* __restrict__ ptok,
    const int* __restrict__ offs, const int* __restrict__ counts,
    u16* __restrict__ h)
{
  const int e = blockIdx.z;
  const int cnt = counts[e];
  const int row0 = blockIdx.y * 128;
  if (row0 >= cnt) return;
  const int off = offs[e];
  const int col0 = blockIdx.x * 128;

  __shared__ __align__(16) u16 As[128 * LSTR];
  __shared__ __align__(16) u16 Bs[128 * LSTR];

  const int tid = threadIdx.x;
  const int lane = tid & 63;
  const int wave = tid >> 6;
  const int wm = wave & 1, wn = wave >> 1;
  const int q = lane >> 4, ml = lane & 15;

  const int sch = tid & 7;     // 16B chunk within 128B row
  const int srow = tid >> 3;   // 0..31

  // A source rows go through the token gather; B rows are linear.
  const u16* asrc[4];
  const u16* bsrc[4];
#pragma unroll
  for (int j = 0; j < 4; j++) {
    int rr = row0 + j * 32 + srow;
    int tk = ptok[off + (rr < cnt ? rr : 0)];
    asrc[j] = xb + (size_t)tk * DM + sch * 8;
    bsrc[j] = w1b + ((size_t)e * DH + col0 + j * 32 + srow) * DM + sch * 8;
  }
  u16* adst = As + tid * 8;    // per-issue j adds j*2048 u16 (=4096 B)
  u16* bdst = Bs + tid * 8;

  const f32x4 z = {0.f, 0.f, 0.f, 0.f};
  f32x4 acc[4][4];
#pragma unroll
  for (int i = 0; i < 4; i++)
#pragma unroll
    for (int j = 0; j < 4; j++) acc[i][j] = z;

  for (int k0 = 0; k0 < DM; k0 += 64) {
#pragma unroll
    for (int j = 0; j < 4; j++) gload_lds16(asrc[j] + k0, adst + j * 2048);
#pragma unroll
    for (int j = 0; j < 4; j++) gload_lds16(bsrc[j] + k0, bdst + j * 2048);
    __syncthreads();
#pragma unroll
    for (int s2 = 0; s2 < 2; s2++) {
      bf16x8 af[4], bv[4];
#pragma unroll
      for (int mt = 0; mt < 4; mt++)
        af[mt] = *(const bf16x8*)&As[(wm * 64 + mt * 16 + ml) * LSTR + s2 * 32 + q * 8];
#pragma unroll
      for (int nt = 0; nt < 4; nt++)
        bv[nt] = *(const bf16x8*)&Bs[(wn * 64 + nt * 16 + ml) * LSTR + s2 * 32 + q * 8];
#pragma unroll
      for (int mt = 0; mt < 4; mt++)
#pragma unroll
        for (int nt = 0; nt < 4; nt++)
          acc[mt][nt] = __builtin_amdgcn_mfma_f32_16x16x32_bf16(af[mt], bv[nt], acc[mt][nt], 0, 0, 0);
    }
    __syncthreads();
  }

#pragma unroll
  for (int mt = 0; mt < 4; mt++) {
#pragma unroll
    for (int reg = 0; reg < 4; reg++) {
      int prow = row0 + wm * 64 + mt * 16 + q * 4 + reg;
      if (prow < cnt) {
#pragma unroll
        for (int nt = 0; nt < 4; nt++) {
          int gcol = col0 + wn * 64 + nt * 16 + ml;
          float v = acc[mt][nt][reg] + b1[e * DH + gcol];
          v = fmaxf(v, 0.f);
          h[(size_t)(off + prow) * DH + gcol] = f2bf(v);
        }
      }
    }
  }
}

// GEMM2: out[tok(p), j] += gate(p) * ( sum_k h[p, k] * w2b[e, j, k] + b2[e, j] )
__global__ __launch_bounds__(256) void gemm2_kernel(
    const u16* __restrict__ h, const u16* __restrict__ w2b,
    const float* __restrict__ b2, const int* __restrict__ ptok,
    const float* __restrict__ pgate,
    const int* __restrict__ offs, const int* __restrict__ counts,
    float* __restrict__ out)
{
  const int e = blockIdx.z;
  const int cnt = counts[e];
  const int row0 = blockIdx.y * 128;
  if (row0 >= cnt) return;
  const int off = offs[e];
  const int col0 = blockIdx.x * 128;

  __shared__ __align__(16) u16 As[128 * LSTR];
  __shared__ __align__(16) u16 Bs[128 * LSTR];

  const int tid = threadIdx.x;
  const int lane = tid & 63;
  const int wave = tid >> 6;
  const int wm = wave & 1, wn = wave >> 1;
  const int q = lane >> 4, ml = lane & 15;

  const int sch = tid & 7;
  const int srow = tid >> 3;

  const u16* asrc[4];
  const u16* bsrc[4];
#pragma unroll
  for (int j = 0; j < 4; j++) {
    int rr = row0 + j * 32 + srow;
    int ar = off + (rr < cnt ? rr : 0);       // clamp OOB rows to a valid row
    asrc[j] = h + (size_t)ar * DH + sch * 8;
    bsrc[j] = w2b + ((size_t)e * DO + col0 + j * 32 + srow) * DH + sch * 8;
  }
  u16* adst = As + tid * 8;
  u16* bdst = Bs + tid * 8;

  const f32x4 z = {0.f, 0.f, 0.f, 0.f};
  f32x4 acc[4][4];
#pragma unroll
  for (int i = 0; i < 4; i++)
#pragma unroll
    for (int j = 0; j < 4; j++) acc[i][j] = z;

  for (int k0 = 0; k0 < DH; k0 += 64) {
#pragma unroll
    for (int j = 0; j < 4; j++) gload_lds16(asrc[j] + k0, adst + j * 2048);
#pragma unroll
    for (int j = 0; j < 4; j++) gload_lds16(bsrc[j] + k0, bdst + j * 2048);
    __syncthreads();
#pragma unroll
    for (int s2 = 0; s2 < 2; s2++) {
      bf16x8 af[4], bv[4];
#pragma unroll
      for (int mt = 0; mt < 4; mt++)
        af[mt] = *(const bf16x8*)&As[(wm * 64 + mt * 16 + ml) * LSTR + s2 * 32 + q * 8];
#pragma unroll
      for (int nt = 0; nt < 4; nt++)
        bv[nt] = *(const bf16x8*)&Bs[(wn * 64 + nt * 16 + ml) * LSTR + s2 * 32 + q * 8];
#pragma unroll
      for (int mt = 0; mt < 4; mt++)
#pragma unroll
        for (int nt = 0; nt < 4; nt++)
          acc[mt][nt] = __builtin_amdgcn_mfma_f32_16x16x32_bf16(af[mt], bv[nt], acc[mt][nt], 0, 0, 0);
    }
    __syncthreads();
  }

#pragma unroll
  for (int mt = 0; mt < 4; mt++) {
#pragma unroll
    for (int reg = 0; reg < 4; reg++) {
      int prow = row0 + wm * 64 + mt * 16 + q * 4 + reg;
      if (prow < cnt) {
        int t = ptok[off + prow];
        float g = pgate[off + prow];
#pragma unroll
        for (int nt = 0; nt < 4; nt++) {
          int gcol = col0 + wn * 64 + nt * 16 + ml;
          float v = acc[mt][nt][reg] + b2[e * DO + gcol];
          atomicAdd(&out[(size_t)t * DO + gcol], g * v);
        }
      }
    }
  }
}

__global__ void loss_kernel(const int* __restrict__ counts, const float* __restrict__ psum,
                            float* __restrict__ out, size_t idx, int T) {
  if (threadIdx.x == 0 && blockIdx.x == 0) {
    float s = 0.f;
    for (int e = 0; e < NE; e++)
      s += ((float)counts[e] / (float)(T * 2)) * (psum[e] / (float)T);
    out[idx] = 0.01f * 8.0f * s;
  }
}

extern "C" void kernel_launch(void* const* d_in, const int* in_sizes, int n_in,
                              void* d_out, int out_size, void* d_ws, size_t ws_size,
                              hipStream_t stream) {
  const float* x  = (const float*)d_in[0];
  const float* rw = (const float*)d_in[1];
  const float* rb = (const float*)d_in[2];
  const float* w1 = (const float*)d_in[3];
  const float* b1 = (const float*)d_in[4];
  const float* w2 = (const float*)d_in[5];
  const float* b2 = (const float*)d_in[6];
  float* out = (float*)d_out;
  char* ws = (char*)d_ws;

  u16* xb    = (u16*)(ws + XB_OFF);
  u16* w1b   = (u16*)(ws + W1B_OFF);
  u16* w2b   = (u16*)(ws + W2B_OFF);
  u16* h     = (u16*)(ws + H_OFF);
  int* ptok  = (int*)(ws + PT_OFF);
  float* pgate = (float*)(ws + PG_OFF);
  int* tidx  = (int*)(ws + TI_OFF);
  float* tgate = (float*)(ws + TG_OFF);
  int* counts = (int*)(ws + ST_OFF);
  int* cursor = (int*)(ws + ST_OFF + 32);
  int* offs   = (int*)(ws + ST_OFF + 64);
  float* psum = (float*)(ws + ST_OFF + 96);

  hipMemsetAsync(d_out, 0, (size_t)out_size * sizeof(float), stream);
  hipMemsetAsync(ws + ST_OFF, 0, 256, stream);

  cast_f32_bf16<<<(T_TOKENS * DM / 4 + 255) / 256, 256, 0, stream>>>(x, xb, T_TOKENS * DM / 4);
  cast_f32_bf16<<<(NE * DH * DM / 4 + 255) / 256, 256, 0, stream>>>(w1, w1b, NE * DH * DM / 4);

  router_kernel<<<T_TOKENS / 4, 256, 0, stream>>>(x, rw, rb, tidx, tgate, counts, psum);
  offsets_kernel<<<1, 64, 0, stream>>>(counts, offs);
  scatter_kernel<<<T_TOKENS / 256, 256, 0, stream>>>(tidx, tgate, offs, cursor, ptok, pgate);

  gemm1_kernel<<<dim3(DH / 128, T_TOKENS / 128, NE), 256, 0, stream>>>(
      xb, w1b, b1, ptok, offs, counts, h);

  cast_f32_bf16<<<(NE * DO * DH / 4 + 255) / 256, 256, 0, stream>>>(w2, w2b, NE * DO * DH / 4);

  gemm2_kernel<<<dim3(DO / 128, T_TOKENS / 128, NE), 256, 0, stream>>>(
      h, w2b, b2, ptok, pgate, offs, counts, out);

  loss_kernel<<<1, 1, 0, stream>>>(counts, psum, out, (size_t)out_size - 1, T_TOKENS);
}

// Round 3
// 911.369 us; speedup vs baseline: 1.1659x; 1.1659x over previous
//
#include <hip/hip_runtime.h>

typedef unsigned short u16;
typedef __bf16 bf16x8 __attribute__((ext_vector_type(8)));
typedef float f32x4 __attribute__((ext_vector_type(4)));

#define T_TOKENS 8192
#define DM 1024
#define DH 4096
#define DO 1024
#define NE 8

// workspace layout (bytes)
#define XB_OFF   0ull
#define W1B_OFF  16777216ull
#define W2B_OFF  16777216ull      /* aliases w1b region; cast after gemm1 */
#define H_OFF    83886080ull      /* 16384 x 4096 bf16 = 128 MB */
#define PT_OFF   218103808ull     /* pair_token [16384] int */
#define PG_OFF   218169344ull     /* pair_gate  [16384] float */
#define TI_OFF   218234880ull     /* topk_idx [8192][2] int */
#define TG_OFF   218300416ull     /* topk_gate [8192][2] float */
#define ST_OFF   218365952ull     /* counts[8], cursor[8], offs[8], psum[8] */

// BK=32: per-buffer stage = A 8KB + B 8KB; double buffer = 32KB LDS total.
// LDS layout swizzle: 16B chunk c of row r stored at chunk-pos c ^ ((r>>1)&3).
// DMA dst is lane-linear (base + tid*16B); we permute the SOURCE chunk per lane
// so the swizzled layout lands correctly. Fragment ds_reads then spread across
// all 8 bank-quads (2-way max aliasing = free).

typedef __attribute__((address_space(3))) void lds_void;
typedef __attribute__((address_space(1))) const void gbl_void;

__device__ __forceinline__ void gload_lds16(const void* g, void* l) {
  __builtin_amdgcn_global_load_lds((gbl_void*)g, (lds_void*)l, 16, 0, 0);
}

__device__ __forceinline__ u16 f2bf(float f) {
  union { float f; unsigned u; } a; a.f = f;
  unsigned u = a.u;
  return (u16)((u + 0x7FFFu + ((u >> 16) & 1u)) >> 16);  // RNE
}

__global__ __launch_bounds__(256) void cast_f32_bf16(const float* __restrict__ src,
                                                     u16* __restrict__ dst, int n4) {
  int i = blockIdx.x * 256 + threadIdx.x;
  if (i >= n4) return;
  float4 v = ((const float4*)src)[i];
  ushort4 o;
  o.x = f2bf(v.x); o.y = f2bf(v.y); o.z = f2bf(v.z); o.w = f2bf(v.w);
  ((ushort4*)dst)[i] = o;
}

__global__ __launch_bounds__(256) void router_kernel(
    const float* __restrict__ x, const float* __restrict__ rw,
    const float* __restrict__ rb,
    int* __restrict__ tidx, float* __restrict__ tgate,
    int* __restrict__ counts, float* __restrict__ psum)
{
  __shared__ float srw[NE * DM];
  __shared__ float s_psum[NE];
  __shared__ int s_cnt[NE];

  for (int i = threadIdx.x; i < NE * DM; i += 256) srw[i] = rw[i];
  if (threadIdx.x < NE) { s_psum[threadIdx.x] = 0.f; s_cnt[threadIdx.x] = 0; }
  __syncthreads();

  const int wave = threadIdx.x >> 6;
  const int lane = threadIdx.x & 63;
  const int t = blockIdx.x * 4 + wave;

  float xv[16];
#pragma unroll
  for (int i = 0; i < 16; i++) xv[i] = x[(size_t)t * DM + i * 64 + lane];

  float logits[8];
#pragma unroll
  for (int e = 0; e < 8; e++) {
    float p = 0.f;
#pragma unroll
    for (int i = 0; i < 16; i++) p += xv[i] * srw[e * DM + i * 64 + lane];
#pragma unroll
    for (int o = 32; o > 0; o >>= 1) p += __shfl_xor(p, o, 64);
    logits[e] = p;
  }

  if (lane == 0) {
    float pe[8];
    float mx = -1e30f;
    for (int e = 0; e < 8; e++) { logits[e] += rb[e]; mx = fmaxf(mx, logits[e]); }
    float s = 0.f;
    for (int e = 0; e < 8; e++) { pe[e] = expf(logits[e] - mx); s += pe[e]; }
    float inv = 1.f / s;
    for (int e = 0; e < 8; e++) { pe[e] *= inv; atomicAdd(&s_psum[e], pe[e]); }
    int i0 = 0;
    for (int e = 1; e < 8; e++) if (pe[e] > pe[i0]) i0 = e;        // ties -> lowest idx
    int i1 = (i0 == 0) ? 1 : 0;
    for (int e = 0; e < 8; e++) if (e != i0 && pe[e] > pe[i1]) i1 = e;
    float g = pe[i0] + pe[i1];
    tidx[t * 2] = i0; tidx[t * 2 + 1] = i1;
    tgate[t * 2] = pe[i0] / g; tgate[t * 2 + 1] = pe[i1] / g;
    atomicAdd(&s_cnt[i0], 1); atomicAdd(&s_cnt[i1], 1);
  }
  __syncthreads();
  if (threadIdx.x < NE) {
    atomicAdd(&counts[threadIdx.x], s_cnt[threadIdx.x]);
    atomicAdd(&psum[threadIdx.x], s_psum[threadIdx.x]);
  }
}

__global__ void offsets_kernel(const int* __restrict__ counts, int* __restrict__ offs) {
  if (threadIdx.x == 0) {
    int a = 0;
    for (int e = 0; e < NE; e++) { offs[e] = a; a += counts[e]; }
  }
}

__global__ __launch_bounds__(256) void scatter_kernel(
    const int* __restrict__ tidx, const float* __restrict__ tgate,
    const int* __restrict__ offs, int* __restrict__ cursor,
    int* __restrict__ ptok, float* __restrict__ pgate)
{
  int t = blockIdx.x * 256 + threadIdx.x;
#pragma unroll
  for (int k = 0; k < 2; k++) {
    int e = tidx[t * 2 + k];
    int pos = offs[e] + atomicAdd(&cursor[e], 1);
    ptok[pos] = t;
    pgate[pos] = tgate[t * 2 + k];
  }
}

// Shared GEMM core: C[128 x 128] tile, BK=32, double-buffered DMA staging,
// one barrier per K-iter.  A rows come from row-gather pointers, B rows linear.
// KD = K depth (elements). Template over epilogue via caller duplication.

#define GEMM_CORE_DECLS                                                        \
  __shared__ __align__(16) u16 sm[16384]; /* [2][A 4096 | B 4096] u16 */       \
  const int tid = threadIdx.x;                                                 \
  const int lane = tid & 63;                                                   \
  const int wave = tid >> 6;                                                   \
  const int wm = wave & 1, wn = wave >> 1;                                     \
  const int q = lane >> 4, ml = lane & 15;                                     \
  const int schunk = (tid & 3) ^ ((tid >> 3) & 3); /* swizzled src chunk */    \
  const int srow = tid >> 2;                      /* 0..63, + j*64 */          \
  const int fsw = (q ^ ((ml >> 1) & 3)) * 8;      /* frag chunk offset (u16) */\
  int offA[4], offB[4];                                                        \
  _Pragma("unroll") for (int t4 = 0; t4 < 4; t4++) {                           \
    offA[t4] = (wm * 64 + t4 * 16 + ml) * 32 + fsw;                            \
    offB[t4] = 4096 + (wn * 64 + t4 * 16 + ml) * 32 + fsw;                     \
  }                                                                            \
  const f32x4 z = {0.f, 0.f, 0.f, 0.f};                                        \
  f32x4 acc[4][4];                                                             \
  _Pragma("unroll") for (int i = 0; i < 4; i++)                                \
    _Pragma("unroll") for (int j = 0; j < 4; j++) acc[i][j] = z;

#define GEMM_STAGE(buf, k0)                                                    \
  {                                                                            \
    u16* dst = sm + (buf) * 8192 + tid * 8;                                    \
    gload_lds16(aptr0 + (k0), dst);                                            \
    gload_lds16(aptr1 + (k0), dst + 2048);                                     \
    gload_lds16(bptr0 + (k0), dst + 4096);                                     \
    gload_lds16(bptr1 + (k0), dst + 6144);                                     \
  }

#define GEMM_KLOOP(KD)                                                         \
  GEMM_STAGE(0, 0)                                                             \
  int cur = 0;                                                                 \
  for (int k0 = 0; k0 < (KD); k0 += 32) {                                      \
    __syncthreads();                                                           \
    if (k0 + 32 < (KD)) { GEMM_STAGE(cur ^ 1, k0 + 32) }                       \
    const u16* Ab = sm + cur * 8192;                                           \
    bf16x8 af[4], bv[4];                                                       \
    _Pragma("unroll") for (int mt = 0; mt < 4; mt++)                           \
      af[mt] = *(const bf16x8*)&Ab[offA[mt]];                                  \
    _Pragma("unroll") for (int nt = 0; nt < 4; nt++)                           \
      bv[nt] = *(const bf16x8*)&Ab[offB[nt]];                                  \
    _Pragma("unroll") for (int mt = 0; mt < 4; mt++)                           \
      _Pragma("unroll") for (int nt = 0; nt < 4; nt++)                         \
        acc[mt][nt] =                                                          \
            __builtin_amdgcn_mfma_f32_16x16x32_bf16(af[mt], bv[nt],            \
                                                    acc[mt][nt], 0, 0, 0);     \
    cur ^= 1;                                                                  \
  }

// GEMM1: h[p, j] = relu( sum_k xb[tok(p), k] * w1b[e, j, k] + b1[e, j] )
__global__ __launch_bounds__(256) void gemm1_kernel(
    const u16* __restrict__ xb, const u16* __restrict__ w1b,
    const float* __restrict__ b1, const int* __restrict__ ptok,
    const int* __restrict__ offs, const int* __restrict__ counts,
    u16* __restrict__ h)
{
  const int e = blockIdx.z;
  const int cnt = counts[e];
  const int row0 = blockIdx.y * 128;
  if (row0 >= cnt) return;
  const int off = offs[e];
  const int col0 = blockIdx.x * 128;

  GEMM_CORE_DECLS

  int ra0 = row0 + srow, ra1 = row0 + 64 + srow;
  int tk0 = ptok[off + (ra0 < cnt ? ra0 : 0)];
  int tk1 = ptok[off + (ra1 < cnt ? ra1 : 0)];
  const u16* aptr0 = xb + (size_t)tk0 * DM + schunk * 8;
  const u16* aptr1 = xb + (size_t)tk1 * DM + schunk * 8;
  const u16* bptr0 = w1b + ((size_t)e * DH + col0 + srow) * DM + schunk * 8;
  const u16* bptr1 = w1b + ((size_t)e * DH + col0 + 64 + srow) * DM + schunk * 8;

  GEMM_KLOOP(DM)

#pragma unroll
  for (int mt = 0; mt < 4; mt++) {
#pragma unroll
    for (int reg = 0; reg < 4; reg++) {
      int prow = row0 + wm * 64 + mt * 16 + q * 4 + reg;
      if (prow < cnt) {
#pragma unroll
        for (int nt = 0; nt < 4; nt++) {
          int gcol = col0 + wn * 64 + nt * 16 + ml;
          float v = acc[mt][nt][reg] + b1[e * DH + gcol];
          v = fmaxf(v, 0.f);
          h[(size_t)(off + prow) * DH + gcol] = f2bf(v);
        }
      }
    }
  }
}

// GEMM2: out[tok(p), j] += gate(p) * ( sum_k h[p, k] * w2b[e, j, k] + b2[e, j] )
__global__ __launch_bounds__(256) void gemm2_kernel(
    const u16* __restrict__ h, const u16* __restrict__ w2b,
    const float* __restrict__ b2, const int* __restrict__ ptok,
    const float* __restrict__ pgate,
    const int* __restrict__ offs, const int* __restrict__ counts,
    float* __restrict__ out)
{
  const int e = blockIdx.z;
  const int cnt = counts[e];
  const int row0 = blockIdx.y * 128;
  if (row0 >= cnt) return;
  const int off = offs[e];
  const int col0 = blockIdx.x * 128;

  GEMM_CORE_DECLS

  int ra0 = row0 + srow, ra1 = row0 + 64 + srow;
  int ar0 = off + (ra0 < cnt ? ra0 : 0);
  int ar1 = off + (ra1 < cnt ? ra1 : 0);
  const u16* aptr0 = h + (size_t)ar0 * DH + schunk * 8;
  const u16* aptr1 = h + (size_t)ar1 * DH + schunk * 8;
  const u16* bptr0 = w2b + ((size_t)e * DO + col0 + srow) * DH + schunk * 8;
  const u16* bptr1 = w2b + ((size_t)e * DO + col0 + 64 + srow) * DH + schunk * 8;

  GEMM_KLOOP(DH)

#pragma unroll
  for (int mt = 0; mt < 4; mt++) {
#pragma unroll
    for (int reg = 0; reg < 4; reg++) {
      int prow = row0 + wm * 64 + mt * 16 + q * 4 + reg;
      if (prow < cnt) {
        int t = ptok[off + prow];
        float g = pgate[off + prow];
#pragma unroll
        for (int nt = 0; nt < 4; nt++) {
          int gcol = col0 + wn * 64 + nt * 16 + ml;
          float v = acc[mt][nt][reg] + b2[e * DO + gcol];
          atomicAdd(&out[(size_t)t * DO + gcol], g * v);
        }
      }
    }
  }
}

__global__ void loss_kernel(const int* __restrict__ counts, const float* __restrict__ psum,
                            float* __restrict__ out, size_t idx, int T) {
  if (threadIdx.x == 0 && blockIdx.x == 0) {
    float s = 0.f;
    for (int e = 0; e < NE; e++)
      s += ((float)counts[e] / (float)(T * 2)) * (psum[e] / (float)T);
    out[idx] = 0.01f * 8.0f * s;
  }
}

extern "C" void kernel_launch(void* const* d_in, const int* in_sizes, int n_in,
                              void* d_out, int out_size, void* d_ws, size_t ws_size,
                              hipStream_t stream) {
  const float* x  = (const float*)d_in[0];
  const float* rw = (const float*)d_in[1];
  const float* rb = (const float*)d_in[2];
  const float* w1 = (const float*)d_in[3];
  const float* b1 = (const float*)d_in[4];
  const float* w2 = (const float*)d_in[5];
  const float* b2 = (const float*)d_in[6];
  float* out = (float*)d_out;
  char* ws = (char*)d_ws;

  u16* xb    = (u16*)(ws + XB_OFF);
  u16* w1b   = (u16*)(ws + W1B_OFF);
  u16* w2b   = (u16*)(ws + W2B_OFF);
  u16* h     = (u16*)(ws + H_OFF);
  int* ptok  = (int*)(ws + PT_OFF);
  float* pgate = (float*)(ws + PG_OFF);
  int* tidx  = (int*)(ws + TI_OFF);
  float* tgate = (float*)(ws + TG_OFF);
  int* counts = (int*)(ws + ST_OFF);
  int* cursor = (int*)(ws + ST_OFF + 32);
  int* offs   = (int*)(ws + ST_OFF + 64);
  float* psum = (float*)(ws + ST_OFF + 96);

  hipMemsetAsync(d_out, 0, (size_t)out_size * sizeof(float), stream);
  hipMemsetAsync(ws + ST_OFF, 0, 256, stream);

  cast_f32_bf16<<<(T_TOKENS * DM / 4 + 255) / 256, 256, 0, stream>>>(x, xb, T_TOKENS * DM / 4);
  cast_f32_bf16<<<(NE * DH * DM / 4 + 255) / 256, 256, 0, stream>>>(w1, w1b, NE * DH * DM / 4);

  router_kernel<<<T_TOKENS / 4, 256, 0, stream>>>(x, rw, rb, tidx, tgate, counts, psum);
  offsets_kernel<<<1, 64, 0, stream>>>(counts, offs);
  scatter_kernel<<<T_TOKENS / 256, 256, 0, stream>>>(tidx, tgate, offs, cursor, ptok, pgate);

  gemm1_kernel<<<dim3(DH / 128, T_TOKENS / 128, NE), 256, 0, stream>>>(
      xb, w1b, b1, ptok, offs, counts, h);

  cast_f32_bf16<<<(NE * DO * DH / 4 + 255) / 256, 256, 0, stream>>>(w2, w2b, NE * DO * DH / 4);

  gemm2_kernel<<<dim3(DO / 128, T_TOKENS / 128, NE), 256, 0, stream>>>(
      h, w2b, b2, ptok, pgate, offs, counts, out);

  loss_kernel<<<1, 1, 0, stream>>>(counts, psum, out, (size_t)out_size - 1, T_TOKENS);
}